// Round 5
// baseline (363.950 us; speedup 1.0000x reference)
//
#include <hip/hip_runtime.h>

#define BINS 10

// bin id: reference floor(g * (10 - 1e-4)); identical fp32 ops -> bit-match
__device__ __forceinline__ int bin_of(float xx, float tt) {
    float g = fabsf(xx - tt);
    int b = (int)(g * 9.9999f);
    return b > (BINS - 1) ? (BINS - 1) : b;
}

__device__ __forceinline__ float loss_of(float xx, float tt) {
    return -(tt * __logf(xx) + (1.0f - tt) * __logf(1.0f - xx));
}

// Flat-path accumulate: sums via 3-VALU/bin cndmask ladder; counts via a
// single packed u64 (10 bins x 5-bit fields; per-lane count <= 16 fits).
// ~4 VALU/elem for counts vs ~20 for a u32 ladder.
__device__ __forceinline__ void accum_flat(float xx, float tt,
                                           float* __restrict__ sum,
                                           unsigned long long& cpack) {
    int b = bin_of(xx, tt);
    float loss = loss_of(xx, tt);
    cpack += 1ull << (5 * b);
#pragma unroll
    for (int k = 0; k < BINS; ++k)
        sum[k] += (b == k) ? loss : 0.0f;
}

// ---------------------------------------------------------------------------
// Flat kernel: NO LOOP. Each lane owns exactly 16 elements (4 float4 pairs).
// All 8 dwordx4 loads are issued straight-line at the top -> 128 B/lane in
// flight (the in-loop scheduler kept MLP at ~2 for three rounds; VGPR=16/36
// proved it). Latency across blocks is hidden by oversubscription: 8192
// blocks = 32 blocks/CU dispatched over the kernel, ~8 resident, load and
// compute phases of different blocks overlap freely.
// Requires N % 4096 == 0 (exact for 16384x2048); else generic path below.
// ---------------------------------------------------------------------------
__global__ __launch_bounds__(256) void ghm_flat(
    const float4* __restrict__ x4, const float4* __restrict__ t4,
    float* __restrict__ psum, unsigned* __restrict__ pcnt, int nb)
{
    int base = blockIdx.x * 1024 + threadIdx.x;  // float4 index, j-stride 256

    // 8 independent coalesced 16 B loads (1 KB/wave each), issued up front.
    float4 xa = x4[base];
    float4 ta = t4[base];
    float4 xb = x4[base + 256];
    float4 tb = t4[base + 256];
    float4 xc = x4[base + 512];
    float4 tc = t4[base + 512];
    float4 xd = x4[base + 768];
    float4 td = t4[base + 768];

    float sum[BINS];
#pragma unroll
    for (int k = 0; k < BINS; ++k) sum[k] = 0.0f;
    unsigned long long cpack = 0ull;

    accum_flat(xa.x, ta.x, sum, cpack);
    accum_flat(xa.y, ta.y, sum, cpack);
    accum_flat(xa.z, ta.z, sum, cpack);
    accum_flat(xa.w, ta.w, sum, cpack);
    accum_flat(xb.x, tb.x, sum, cpack);
    accum_flat(xb.y, tb.y, sum, cpack);
    accum_flat(xb.z, tb.z, sum, cpack);
    accum_flat(xb.w, tb.w, sum, cpack);
    accum_flat(xc.x, tc.x, sum, cpack);
    accum_flat(xc.y, tc.y, sum, cpack);
    accum_flat(xc.z, tc.z, sum, cpack);
    accum_flat(xc.w, tc.w, sum, cpack);
    accum_flat(xd.x, td.x, sum, cpack);
    accum_flat(xd.y, td.y, sum, cpack);
    accum_flat(xd.z, td.z, sum, cpack);
    accum_flat(xd.w, td.w, sum, cpack);

    // unpack counts (<= 16 per bin per lane)
    unsigned cnt[BINS];
#pragma unroll
    for (int k = 0; k < BINS; ++k)
        cnt[k] = (unsigned)((cpack >> (5 * k)) & 31ull);

    // wave(64) shuffle reduction
#pragma unroll
    for (int k = 0; k < BINS; ++k) {
#pragma unroll
        for (int off = 32; off > 0; off >>= 1) {
            sum[k] += __shfl_down(sum[k], off, 64);
            cnt[k] += (unsigned)__shfl_down((int)cnt[k], off, 64);
        }
    }

    __shared__ float s_sum[4][BINS];
    __shared__ unsigned s_cnt[4][BINS];
    int lane = threadIdx.x & 63;
    int wv = threadIdx.x >> 6;
    if (lane == 0) {
#pragma unroll
        for (int k = 0; k < BINS; ++k) { s_sum[wv][k] = sum[k]; s_cnt[wv][k] = cnt[k]; }
    }
    __syncthreads();
    if (threadIdx.x < BINS) {
        float s = 0.0f;
        unsigned c = 0u;
#pragma unroll
        for (int w = 0; w < 4; ++w) { s += s_sum[w][threadIdx.x]; c += s_cnt[w][threadIdx.x]; }
        // bin-major layout: finalizer reads coalesced runs per bin
        psum[(size_t)threadIdx.x * nb + blockIdx.x] = s;
        pcnt[(size_t)threadIdx.x * nb + blockIdx.x] = c;
    }
}

// Finalize for the bin-major flat path: per-bin coalesced block reduction.
__global__ __launch_bounds__(256) void ghm_final_bm(
    const float* __restrict__ psum, const unsigned* __restrict__ pcnt,
    float* __restrict__ out, int nb, float Nf)
{
    __shared__ float s_s[4];
    __shared__ unsigned s_c[4];
    __shared__ float tot_s[BINS];
    __shared__ unsigned tot_c[BINS];
    int lane = threadIdx.x & 63;
    int wv = threadIdx.x >> 6;

    for (int k = 0; k < BINS; ++k) {
        float s = 0.0f;
        unsigned c = 0u;
        for (int i = threadIdx.x; i < nb; i += 256) {
            s += psum[(size_t)k * nb + i];
            c += pcnt[(size_t)k * nb + i];
        }
#pragma unroll
        for (int off = 32; off > 0; off >>= 1) {
            s += __shfl_down(s, off, 64);
            c += (unsigned)__shfl_down((int)c, off, 64);
        }
        if (lane == 0) { s_s[wv] = s; s_c[wv] = c; }
        __syncthreads();
        if (threadIdx.x == 0) {
            tot_s[k] = s_s[0] + s_s[1] + s_s[2] + s_s[3];
            tot_c[k] = s_c[0] + s_c[1] + s_c[2] + s_c[3];
        }
        __syncthreads();
    }

    if (threadIdx.x == 0) {
        float nonempty = 0.0f;
#pragma unroll
        for (int k = 0; k < BINS; ++k) nonempty += (tot_c[k] > 0u) ? 1.0f : 0.0f;
        float total = 0.0f;
#pragma unroll
        for (int k = 0; k < BINS; ++k) {
            float gd = (float)tot_c[k] * nonempty;
            gd = gd < 1.0f ? 1.0f : gd;      // clip(gd, 1, None)
            float beta = Nf / gd;
            total += tot_s[k] * beta;
        }
        out[0] = total / Nf;   // mean
    }
}

// ---------------------------------------------------------------------------
// Generic fallback (any N, tiny workspace): R1 structure, verified absmax 0.0.
// ---------------------------------------------------------------------------
__device__ __forceinline__ void accum_gen(float xx, float tt,
                                          float* __restrict__ sum,
                                          unsigned* __restrict__ cnt) {
    int b = bin_of(xx, tt);
    float loss = loss_of(xx, tt);
#pragma unroll
    for (int k = 0; k < BINS; ++k) {
        bool m = (b == k);
        sum[k] += m ? loss : 0.0f;
        cnt[k] += m ? 1u : 0u;
    }
}

template <bool ATOMIC>
__global__ __launch_bounds__(256) void ghm_partial(
    const float* __restrict__ x, const float* __restrict__ t,
    float* __restrict__ psum, unsigned* __restrict__ pcnt,
    int n4, long long n_total)
{
    float sum[BINS];
    unsigned cnt[BINS];
#pragma unroll
    for (int k = 0; k < BINS; ++k) { sum[k] = 0.0f; cnt[k] = 0u; }

    const float4* __restrict__ x4 = (const float4*)x;
    const float4* __restrict__ t4 = (const float4*)t;
    int tid = blockIdx.x * blockDim.x + threadIdx.x;
    int stride = gridDim.x * blockDim.x;

    for (int i = tid; i < n4; i += stride) {
        float4 xv = x4[i];
        float4 tv = t4[i];
        accum_gen(xv.x, tv.x, sum, cnt);
        accum_gen(xv.y, tv.y, sum, cnt);
        accum_gen(xv.z, tv.z, sum, cnt);
        accum_gen(xv.w, tv.w, sum, cnt);
    }
    long long tail_base = (long long)n4 * 4;
    long long rem = n_total - tail_base;
    if ((long long)tid < rem) {
        accum_gen(x[tail_base + tid], t[tail_base + tid], sum, cnt);
    }

#pragma unroll
    for (int k = 0; k < BINS; ++k) {
#pragma unroll
        for (int off = 32; off > 0; off >>= 1) {
            sum[k] += __shfl_down(sum[k], off, 64);
            cnt[k] += (unsigned)__shfl_down((int)cnt[k], off, 64);
        }
    }

    __shared__ float s_sum[4][BINS];
    __shared__ unsigned s_cnt[4][BINS];
    int lane = threadIdx.x & 63;
    int wv = threadIdx.x >> 6;
    if (lane == 0) {
#pragma unroll
        for (int k = 0; k < BINS; ++k) { s_sum[wv][k] = sum[k]; s_cnt[wv][k] = cnt[k]; }
    }
    __syncthreads();
    if (threadIdx.x < BINS) {
        float s = 0.0f;
        unsigned c = 0u;
#pragma unroll
        for (int w = 0; w < 4; ++w) { s += s_sum[w][threadIdx.x]; c += s_cnt[w][threadIdx.x]; }
        if (ATOMIC) {
            atomicAdd(&psum[threadIdx.x], s);
            atomicAdd(&pcnt[threadIdx.x], c);
        } else {
            psum[(size_t)blockIdx.x * BINS + threadIdx.x] = s;
            pcnt[(size_t)blockIdx.x * BINS + threadIdx.x] = c;
        }
    }
}

__global__ void ghm_zero(float* psum, unsigned* pcnt) {
    if (threadIdx.x < BINS) { psum[threadIdx.x] = 0.0f; pcnt[threadIdx.x] = 0u; }
}

// Row-major finalize for the generic path.
__global__ __launch_bounds__(256) void ghm_final(
    const float* __restrict__ psum, const unsigned* __restrict__ pcnt,
    float* __restrict__ out, int nblocks, float Nf)
{
    float sum[BINS];
    unsigned cnt[BINS];
#pragma unroll
    for (int k = 0; k < BINS; ++k) { sum[k] = 0.0f; cnt[k] = 0u; }

    for (int i = threadIdx.x; i < nblocks; i += blockDim.x) {
#pragma unroll
        for (int k = 0; k < BINS; ++k) {
            sum[k] += psum[(size_t)i * BINS + k];
            cnt[k] += pcnt[(size_t)i * BINS + k];
        }
    }

#pragma unroll
    for (int k = 0; k < BINS; ++k) {
#pragma unroll
        for (int off = 32; off > 0; off >>= 1) {
            sum[k] += __shfl_down(sum[k], off, 64);
            cnt[k] += (unsigned)__shfl_down((int)cnt[k], off, 64);
        }
    }

    __shared__ float s_sum[4][BINS];
    __shared__ unsigned s_cnt[4][BINS];
    int lane = threadIdx.x & 63;
    int wv = threadIdx.x >> 6;
    if (lane == 0) {
#pragma unroll
        for (int k = 0; k < BINS; ++k) { s_sum[wv][k] = sum[k]; s_cnt[wv][k] = cnt[k]; }
    }
    __syncthreads();

    if (threadIdx.x == 0) {
        float tot_s[BINS];
        unsigned tot_c[BINS];
#pragma unroll
        for (int k = 0; k < BINS; ++k) {
            float s = 0.0f;
            unsigned c = 0u;
#pragma unroll
            for (int w = 0; w < 4; ++w) { s += s_sum[w][k]; c += s_cnt[w][k]; }
            tot_s[k] = s;
            tot_c[k] = c;
        }
        float nonempty = 0.0f;
#pragma unroll
        for (int k = 0; k < BINS; ++k) nonempty += (tot_c[k] > 0u) ? 1.0f : 0.0f;
        float total = 0.0f;
#pragma unroll
        for (int k = 0; k < BINS; ++k) {
            float gd = (float)tot_c[k] * nonempty;
            gd = gd < 1.0f ? 1.0f : gd;      // clip(gd, 1, None)
            float beta = Nf / gd;
            total += tot_s[k] * beta;
        }
        out[0] = total / Nf;   // mean
    }
}

extern "C" void kernel_launch(void* const* d_in, const int* in_sizes, int n_in,
                              void* d_out, int out_size, void* d_ws, size_t ws_size,
                              hipStream_t stream) {
    const float* x = (const float*)d_in[0];
    const float* t = (const float*)d_in[1];
    float* out = (float*)d_out;

    long long N = (long long)in_sizes[0];
    int n4 = (int)(N / 4);
    float Nf = (float)N;

    // Flat path: exact tiling, 16 elements per lane, no loops.
    if (N % 4096 == 0 && N / 4096 <= 0x7fffffffLL) {
        int nb = (int)(N / 4096);
        size_t need = (size_t)nb * BINS * (sizeof(float) + sizeof(unsigned));
        if (ws_size >= need) {
            float* psum = (float*)d_ws;
            unsigned* pcnt = (unsigned*)(psum + (size_t)BINS * nb);
            ghm_flat<<<nb, 256, 0, stream>>>((const float4*)x, (const float4*)t,
                                             psum, pcnt, nb);
            ghm_final_bm<<<1, 256, 0, stream>>>(psum, pcnt, out, nb, Nf);
            return;
        }
    }

    // Generic fallback.
    const int nblocks = 2048;
    const size_t per_block = (size_t)BINS * (sizeof(float) + sizeof(unsigned)); // 80 B
    if (ws_size >= (size_t)nblocks * per_block) {
        float* psum = (float*)d_ws;
        unsigned* pcnt = (unsigned*)(psum + (size_t)nblocks * BINS);
        ghm_partial<false><<<nblocks, 256, 0, stream>>>(x, t, psum, pcnt, n4, N);
        ghm_final<<<1, 256, 0, stream>>>(psum, pcnt, out, nblocks, Nf);
    } else {
        float* psum = (float*)d_ws;
        unsigned* pcnt = (unsigned*)(psum + BINS);
        ghm_zero<<<1, 64, 0, stream>>>(psum, pcnt);
        ghm_partial<true><<<nblocks, 256, 0, stream>>>(x, t, psum, pcnt, n4, N);
        ghm_final<<<1, 256, 0, stream>>>(psum, pcnt, out, 1, Nf);
    }
}

// Round 6
// 362.356 us; speedup vs baseline: 1.0044x; 1.0044x over previous
//
#include <hip/hip_runtime.h>

#define BINS 10

// bin id: reference floor(g * (10 - 1e-4)); identical fp32 ops -> bit-match
__device__ __forceinline__ int bin_of(float xx, float tt) {
    float g = fabsf(xx - tt);
    int b = (int)(g * 9.9999f);
    return b > (BINS - 1) ? (BINS - 1) : b;
}

__device__ __forceinline__ float loss_of(float xx, float tt) {
    return -(tt * __logf(xx) + (1.0f - tt) * __logf(1.0f - xx));
}

// Flat-path accumulate: sums via 3-VALU/bin cndmask ladder; counts via a
// single packed u64 (10 bins x 5-bit fields; per-lane count <= 16 fits).
__device__ __forceinline__ void accum_flat(float xx, float tt,
                                           float* __restrict__ sum,
                                           unsigned long long& cpack) {
    int b = bin_of(xx, tt);
    float loss = loss_of(xx, tt);
    cpack += 1ull << (5 * b);
#pragma unroll
    for (int k = 0; k < BINS; ++k)
        sum[k] += (b == k) ? loss : 0.0f;
}

// ---------------------------------------------------------------------------
// Flat kernel, R6 change: __builtin_amdgcn_sched_barrier(0) between the load
// block and the compute block. R5 proved (VGPR_Count=28) that without a
// scheduling fence the machine scheduler re-sinks the 8 up-front loads to ~2
// in flight; 2 KB/wave outstanding x ~700cy latency == the observed 2.6 TB/s
// ceiling. The fence forces all 8 dwordx4 (8 KB/wave) in flight; waits then
// roll as counted vmcnt at each value's first use (load order == use order).
// ---------------------------------------------------------------------------
__global__ __launch_bounds__(256) void ghm_flat(
    const float4* __restrict__ x4, const float4* __restrict__ t4,
    float* __restrict__ psum, unsigned* __restrict__ pcnt, int nb)
{
    int base = blockIdx.x * 1024 + threadIdx.x;  // float4 index, j-stride 256

    // 8 independent coalesced 16 B loads (1 KB/wave each), issued up front,
    // in exactly the order they are consumed below.
    float4 xa = x4[base];
    float4 ta = t4[base];
    float4 xb = x4[base + 256];
    float4 tb = t4[base + 256];
    float4 xc = x4[base + 512];
    float4 tc = t4[base + 512];
    float4 xd = x4[base + 768];
    float4 td = t4[base + 768];

    // Scheduling fence: nothing moves across (neither loads sink below nor
    // compute hoists above). NOT a memory barrier -- waitcnt insertion stays
    // dependence-driven, so consumption gets rolling vmcnt(6/4/2/0).
    __builtin_amdgcn_sched_barrier(0);

    float sum[BINS];
#pragma unroll
    for (int k = 0; k < BINS; ++k) sum[k] = 0.0f;
    unsigned long long cpack = 0ull;

    accum_flat(xa.x, ta.x, sum, cpack);
    accum_flat(xa.y, ta.y, sum, cpack);
    accum_flat(xa.z, ta.z, sum, cpack);
    accum_flat(xa.w, ta.w, sum, cpack);
    accum_flat(xb.x, tb.x, sum, cpack);
    accum_flat(xb.y, tb.y, sum, cpack);
    accum_flat(xb.z, tb.z, sum, cpack);
    accum_flat(xb.w, tb.w, sum, cpack);
    accum_flat(xc.x, tc.x, sum, cpack);
    accum_flat(xc.y, tc.y, sum, cpack);
    accum_flat(xc.z, tc.z, sum, cpack);
    accum_flat(xc.w, tc.w, sum, cpack);
    accum_flat(xd.x, td.x, sum, cpack);
    accum_flat(xd.y, td.y, sum, cpack);
    accum_flat(xd.z, td.z, sum, cpack);
    accum_flat(xd.w, td.w, sum, cpack);

    // unpack counts (<= 16 per bin per lane)
    unsigned cnt[BINS];
#pragma unroll
    for (int k = 0; k < BINS; ++k)
        cnt[k] = (unsigned)((cpack >> (5 * k)) & 31ull);

    // wave(64) shuffle reduction
#pragma unroll
    for (int k = 0; k < BINS; ++k) {
#pragma unroll
        for (int off = 32; off > 0; off >>= 1) {
            sum[k] += __shfl_down(sum[k], off, 64);
            cnt[k] += (unsigned)__shfl_down((int)cnt[k], off, 64);
        }
    }

    __shared__ float s_sum[4][BINS];
    __shared__ unsigned s_cnt[4][BINS];
    int lane = threadIdx.x & 63;
    int wv = threadIdx.x >> 6;
    if (lane == 0) {
#pragma unroll
        for (int k = 0; k < BINS; ++k) { s_sum[wv][k] = sum[k]; s_cnt[wv][k] = cnt[k]; }
    }
    __syncthreads();
    if (threadIdx.x < BINS) {
        float s = 0.0f;
        unsigned c = 0u;
#pragma unroll
        for (int w = 0; w < 4; ++w) { s += s_sum[w][threadIdx.x]; c += s_cnt[w][threadIdx.x]; }
        // bin-major layout: finalizer reads coalesced runs per bin
        psum[(size_t)threadIdx.x * nb + blockIdx.x] = s;
        pcnt[(size_t)threadIdx.x * nb + blockIdx.x] = c;
    }
}

// Finalize for the bin-major flat path: per-bin coalesced block reduction.
__global__ __launch_bounds__(256) void ghm_final_bm(
    const float* __restrict__ psum, const unsigned* __restrict__ pcnt,
    float* __restrict__ out, int nb, float Nf)
{
    __shared__ float s_s[4];
    __shared__ unsigned s_c[4];
    __shared__ float tot_s[BINS];
    __shared__ unsigned tot_c[BINS];
    int lane = threadIdx.x & 63;
    int wv = threadIdx.x >> 6;

    for (int k = 0; k < BINS; ++k) {
        float s = 0.0f;
        unsigned c = 0u;
        for (int i = threadIdx.x; i < nb; i += 256) {
            s += psum[(size_t)k * nb + i];
            c += pcnt[(size_t)k * nb + i];
        }
#pragma unroll
        for (int off = 32; off > 0; off >>= 1) {
            s += __shfl_down(s, off, 64);
            c += (unsigned)__shfl_down((int)c, off, 64);
        }
        if (lane == 0) { s_s[wv] = s; s_c[wv] = c; }
        __syncthreads();
        if (threadIdx.x == 0) {
            tot_s[k] = s_s[0] + s_s[1] + s_s[2] + s_s[3];
            tot_c[k] = s_c[0] + s_c[1] + s_c[2] + s_c[3];
        }
        __syncthreads();
    }

    if (threadIdx.x == 0) {
        float nonempty = 0.0f;
#pragma unroll
        for (int k = 0; k < BINS; ++k) nonempty += (tot_c[k] > 0u) ? 1.0f : 0.0f;
        float total = 0.0f;
#pragma unroll
        for (int k = 0; k < BINS; ++k) {
            float gd = (float)tot_c[k] * nonempty;
            gd = gd < 1.0f ? 1.0f : gd;      // clip(gd, 1, None)
            float beta = Nf / gd;
            total += tot_s[k] * beta;
        }
        out[0] = total / Nf;   // mean
    }
}

// ---------------------------------------------------------------------------
// Generic fallback (any N, tiny workspace): R1 structure, verified absmax 0.0.
// ---------------------------------------------------------------------------
__device__ __forceinline__ void accum_gen(float xx, float tt,
                                          float* __restrict__ sum,
                                          unsigned* __restrict__ cnt) {
    int b = bin_of(xx, tt);
    float loss = loss_of(xx, tt);
#pragma unroll
    for (int k = 0; k < BINS; ++k) {
        bool m = (b == k);
        sum[k] += m ? loss : 0.0f;
        cnt[k] += m ? 1u : 0u;
    }
}

template <bool ATOMIC>
__global__ __launch_bounds__(256) void ghm_partial(
    const float* __restrict__ x, const float* __restrict__ t,
    float* __restrict__ psum, unsigned* __restrict__ pcnt,
    int n4, long long n_total)
{
    float sum[BINS];
    unsigned cnt[BINS];
#pragma unroll
    for (int k = 0; k < BINS; ++k) { sum[k] = 0.0f; cnt[k] = 0u; }

    const float4* __restrict__ x4 = (const float4*)x;
    const float4* __restrict__ t4 = (const float4*)t;
    int tid = blockIdx.x * blockDim.x + threadIdx.x;
    int stride = gridDim.x * blockDim.x;

    for (int i = tid; i < n4; i += stride) {
        float4 xv = x4[i];
        float4 tv = t4[i];
        accum_gen(xv.x, tv.x, sum, cnt);
        accum_gen(xv.y, tv.y, sum, cnt);
        accum_gen(xv.z, tv.z, sum, cnt);
        accum_gen(xv.w, tv.w, sum, cnt);
    }
    long long tail_base = (long long)n4 * 4;
    long long rem = n_total - tail_base;
    if ((long long)tid < rem) {
        accum_gen(x[tail_base + tid], t[tail_base + tid], sum, cnt);
    }

#pragma unroll
    for (int k = 0; k < BINS; ++k) {
#pragma unroll
        for (int off = 32; off > 0; off >>= 1) {
            sum[k] += __shfl_down(sum[k], off, 64);
            cnt[k] += (unsigned)__shfl_down((int)cnt[k], off, 64);
        }
    }

    __shared__ float s_sum[4][BINS];
    __shared__ unsigned s_cnt[4][BINS];
    int lane = threadIdx.x & 63;
    int wv = threadIdx.x >> 6;
    if (lane == 0) {
#pragma unroll
        for (int k = 0; k < BINS; ++k) { s_sum[wv][k] = sum[k]; s_cnt[wv][k] = cnt[k]; }
    }
    __syncthreads();
    if (threadIdx.x < BINS) {
        float s = 0.0f;
        unsigned c = 0u;
#pragma unroll
        for (int w = 0; w < 4; ++w) { s += s_sum[w][threadIdx.x]; c += s_cnt[w][threadIdx.x]; }
        if (ATOMIC) {
            atomicAdd(&psum[threadIdx.x], s);
            atomicAdd(&pcnt[threadIdx.x], c);
        } else {
            psum[(size_t)blockIdx.x * BINS + threadIdx.x] = s;
            pcnt[(size_t)blockIdx.x * BINS + threadIdx.x] = c;
        }
    }
}

__global__ void ghm_zero(float* psum, unsigned* pcnt) {
    if (threadIdx.x < BINS) { psum[threadIdx.x] = 0.0f; pcnt[threadIdx.x] = 0u; }
}

// Row-major finalize for the generic path.
__global__ __launch_bounds__(256) void ghm_final(
    const float* __restrict__ psum, const unsigned* __restrict__ pcnt,
    float* __restrict__ out, int nblocks, float Nf)
{
    float sum[BINS];
    unsigned cnt[BINS];
#pragma unroll
    for (int k = 0; k < BINS; ++k) { sum[k] = 0.0f; cnt[k] = 0u; }

    for (int i = threadIdx.x; i < nblocks; i += blockDim.x) {
#pragma unroll
        for (int k = 0; k < BINS; ++k) {
            sum[k] += psum[(size_t)i * BINS + k];
            cnt[k] += pcnt[(size_t)i * BINS + k];
        }
    }

#pragma unroll
    for (int k = 0; k < BINS; ++k) {
#pragma unroll
        for (int off = 32; off > 0; off >>= 1) {
            sum[k] += __shfl_down(sum[k], off, 64);
            cnt[k] += (unsigned)__shfl_down((int)cnt[k], off, 64);
        }
    }

    __shared__ float s_sum[4][BINS];
    __shared__ unsigned s_cnt[4][BINS];
    int lane = threadIdx.x & 63;
    int wv = threadIdx.x >> 6;
    if (lane == 0) {
#pragma unroll
        for (int k = 0; k < BINS; ++k) { s_sum[wv][k] = sum[k]; s_cnt[wv][k] = cnt[k]; }
    }
    __syncthreads();

    if (threadIdx.x == 0) {
        float tot_s[BINS];
        unsigned tot_c[BINS];
#pragma unroll
        for (int k = 0; k < BINS; ++k) {
            float s = 0.0f;
            unsigned c = 0u;
#pragma unroll
            for (int w = 0; w < 4; ++w) { s += s_sum[w][k]; c += s_cnt[w][k]; }
            tot_s[k] = s;
            tot_c[k] = c;
        }
        float nonempty = 0.0f;
#pragma unroll
        for (int k = 0; k < BINS; ++k) nonempty += (tot_c[k] > 0u) ? 1.0f : 0.0f;
        float total = 0.0f;
#pragma unroll
        for (int k = 0; k < BINS; ++k) {
            float gd = (float)tot_c[k] * nonempty;
            gd = gd < 1.0f ? 1.0f : gd;      // clip(gd, 1, None)
            float beta = Nf / gd;
            total += tot_s[k] * beta;
        }
        out[0] = total / Nf;   // mean
    }
}

extern "C" void kernel_launch(void* const* d_in, const int* in_sizes, int n_in,
                              void* d_out, int out_size, void* d_ws, size_t ws_size,
                              hipStream_t stream) {
    const float* x = (const float*)d_in[0];
    const float* t = (const float*)d_in[1];
    float* out = (float*)d_out;

    long long N = (long long)in_sizes[0];
    int n4 = (int)(N / 4);
    float Nf = (float)N;

    // Flat path: exact tiling, 16 elements per lane, no loops.
    if (N % 4096 == 0 && N / 4096 <= 0x7fffffffLL) {
        int nb = (int)(N / 4096);
        size_t need = (size_t)nb * BINS * (sizeof(float) + sizeof(unsigned));
        if (ws_size >= need) {
            float* psum = (float*)d_ws;
            unsigned* pcnt = (unsigned*)(psum + (size_t)BINS * nb);
            ghm_flat<<<nb, 256, 0, stream>>>((const float4*)x, (const float4*)t,
                                             psum, pcnt, nb);
            ghm_final_bm<<<1, 256, 0, stream>>>(psum, pcnt, out, nb, Nf);
            return;
        }
    }

    // Generic fallback.
    const int nblocks = 2048;
    const size_t per_block = (size_t)BINS * (sizeof(float) + sizeof(unsigned)); // 80 B
    if (ws_size >= (size_t)nblocks * per_block) {
        float* psum = (float*)d_ws;
        unsigned* pcnt = (unsigned*)(psum + (size_t)nblocks * BINS);
        ghm_partial<false><<<nblocks, 256, 0, stream>>>(x, t, psum, pcnt, n4, N);
        ghm_final<<<1, 256, 0, stream>>>(psum, pcnt, out, nblocks, Nf);
    } else {
        float* psum = (float*)d_ws;
        unsigned* pcnt = (unsigned*)(psum + BINS);
        ghm_zero<<<1, 64, 0, stream>>>(psum, pcnt);
        ghm_partial<true><<<nblocks, 256, 0, stream>>>(x, t, psum, pcnt, n4, N);
        ghm_final<<<1, 256, 0, stream>>>(psum, pcnt, out, 1, Nf);
    }
}